// Round 8
// baseline (197.444 us; speedup 1.0000x reference)
//
#include <hip/hip_runtime.h>

typedef __attribute__((ext_vector_type(8))) short short8;
typedef __attribute__((ext_vector_type(4))) short short4_t;
typedef __attribute__((ext_vector_type(2))) float float2_t;
typedef __attribute__((ext_vector_type(4))) float float4_t;
typedef __attribute__((ext_vector_type(4))) int int4_t;
typedef __attribute__((ext_vector_type(2))) unsigned uint2_t;

#define CH_STRIDE 4096        // 64*64 spatial per channel
#define IMG_STRIDE 524288     // 128 channels * 4096
#define HW 4096
#define V520 520              // Vt row stride (shorts); 1040B rows keep 16B align
#define K40 40                // Kt row stride (shorts): 32 d + 8 pad

// float -> bf16 bits, round-to-nearest-even (finite inputs only)
static __device__ __forceinline__ short f2b(float x) {
    unsigned u = __builtin_bit_cast(unsigned, x);
    u = (u + 0x7fffu + ((u >> 16) & 1u)) >> 16;
    return (short)u;
}
static __device__ __forceinline__ float bitsf(unsigned u) { return __builtin_bit_cast(float, u); }
static __device__ __forceinline__ unsigned bitsu(float f) { return __builtin_bit_cast(unsigned, f); }

// Fused CSWin block: flash attention (S^T = K*Q^T, permlane P-exchange,
// O^T = V^T*P^T) + depthwise 3x3 conv rpe from LDS-resident V, one launch.
//
// R8: kill the 8-chunk barrier spine. R0-R7 showed dur is insensitive to
// barriers-per-chunk, LDS traffic, exchange latency, fetch volume (+/-35%),
// instruction count, and block geometry; T ~= 71us fixed + C/waves. The one
// invariant was the chunk-synchronized loop: 16 barrier crossings per block,
// all waves convoying through the same phase latencies 8x serially.
// This version stages the FULL 512-key window (Kt 40KB + Vt 33.3KB = 72.5KB,
// x2 blocks = 145KB <= 160KB) in one coalesced prologue (8 float4/thread),
// takes ONE barrier, then each wave free-runs all 8 K-groups: no barriers,
// no staging, no VMEM in the loop. Waves start at staggered chunks
// ((cc+wv)&7 — lsum/acc accumulation is commutative) to de-phase the 16
// waves across the LDS/VALU/TRANS/MFMA pipes instead of convoying.
// Geometry/per-wave shape otherwise = R7 (grid 512 x 1024 thr, qt=2,
// permlane exchange, conv 2ch/thread).
// Pre-committed reads: dur>=85 & occ~19% -> 145KB forced 1 block/CU (revert);
// flat 74-78 at 2 blocks -> sync structure exonerated, T_fixed is inherent.
__global__ __launch_bounds__(1024) void cswin_fused(
    const float* __restrict__ temp, const float* __restrict__ cw,
    const float* __restrict__ cb, float* __restrict__ out)
{
    __shared__ short Kt[512 * K40];    // [key][d] pad-40, FULL window
    __shared__ short Vt[32 * V520];    // [d][l]   FULL window

    int bx = blockIdx.x;
    int nw = bx >> 6;          // window column 0..7 (high bits: XCD L2 locality)
    int r  = bx & 63;
    int b  = r >> 2;           // batch 0..15
    int n  = r & 3;            // head 0..3

    int t    = threadIdx.x;
    int wv   = t >> 6;         // wave 0..15
    int lane = t & 63;
    int mr   = lane & 15;
    int q    = lane >> 4;

    const float* tq = temp + (size_t)b * 3 * IMG_STRIDE + (size_t)(n * 32) * CH_STRIDE + nw * 8;
    const float* tk = tq + IMG_STRIDE;
    const float* tv = tk + IMG_STRIDE;

    int row0 = wv * 32;        // this wave's 32 q-rows (16 waves x 32 = 512)
    const float qscale = 0.2550348889072310f;   // (1/sqrt(32)) * log2(e)

    // ---- prologue: stage the WHOLE window. 1024 threads = 32 d x 32 quad-
    // slots; thread (ld,qs) handles key-quads qq = qs+32i (i=0..3), keys
    // 4qq..4qq+3 = 4 consecutive floats in global (sp offsets 0-3 or 4-7
    // within a spatial row) -> 8 coalesced float4 loads per thread.
    int ld = t >> 5;           // channel d 0..31
    int qs = t & 31;           // quad-slot
    const float* tkld = tk + (size_t)ld * CH_STRIDE;
    const float* tvld = tv + (size_t)ld * CH_STRIDE;

    float4_t kq[4], vq[4];
    #pragma unroll
    for (int i = 0; i < 4; ++i) {
        int qq = qs + 32 * i;
        int sp = (qq >> 1) * 64 + 4 * (qq & 1);
        kq[i] = *reinterpret_cast<const float4_t*>(tkld + sp);
        vq[i] = *reinterpret_cast<const float4_t*>(tvld + sp);
    }

    // Q fragments (B-operand): lane holds Q[row0+qt*16+mr][q*8+j] * qscale
    // (issued alongside staging stores; independent loads pipeline freely)
    short8 Qf[2];
    #pragma unroll
    for (int qt = 0; qt < 2; ++qt) {
        int l = row0 + qt * 16 + mr;
        int sp = (l >> 3) * 64 + (l & 7);
        short8 f;
        #pragma unroll
        for (int j = 0; j < 8; ++j)
            f[j] = f2b(tq[(q * 8 + j) * CH_STRIDE + sp] * qscale);
        Qf[qt] = f;
    }

    #pragma unroll
    for (int i = 0; i < 4; ++i) {
        int qq = qs + 32 * i;
        int k0 = 4 * qq;
        // K: [key][d] scalar b16 stores (prologue-only; conflicts one-time)
        Kt[(k0 + 0) * K40 + ld] = f2b(kq[i].x);
        Kt[(k0 + 1) * K40 + ld] = f2b(kq[i].y);
        Kt[(k0 + 2) * K40 + ld] = f2b(kq[i].z);
        Kt[(k0 + 3) * K40 + ld] = f2b(kq[i].w);
        // V: [d][key] 4 consecutive keys -> one 8B packed store
        short4_t vs = { f2b(vq[i].x), f2b(vq[i].y), f2b(vq[i].z), f2b(vq[i].w) };
        *reinterpret_cast<short4_t*>(&Vt[ld * V520 + k0]) = vs;
    }

    float4_t zero4 = {0.f, 0.f, 0.f, 0.f};
    float4_t acc[2][2];
    #pragma unroll
    for (int dt = 0; dt < 2; ++dt)
        #pragma unroll
        for (int qt = 0; qt < 2; ++qt)
            acc[dt][qt] = zero4;
    float lsum[2] = {0.f, 0.f};

    __syncthreads();           // the ONLY barrier before the epilogue

    #pragma unroll 2
    for (int cc = 0; cc < 8; ++cc) {
        int ch = (cc + wv) & 7;          // wave-staggered chunk order
        const short* Kr = &Kt[ch * 64 * K40];

        #pragma unroll
        for (int g = 0; g < 2; ++g) {
            // S^T tiles: D[m=key][n=qrow], keys g*32..g*32+31 (local to chunk)
            short8 KaA = *reinterpret_cast<const short8*>(&Kr[((2 * g) * 16 + mr) * K40 + q * 8]);
            short8 KaB = *reinterpret_cast<const short8*>(&Kr[((2 * g + 1) * 16 + mr) * K40 + q * 8]);
            unsigned pa0[2], pa1[2], pb0[2], pb1[2];
            #pragma unroll
            for (int qt = 0; qt < 2; ++qt) {
                float4_t sA = __builtin_amdgcn_mfma_f32_16x16x32_bf16(KaA, Qf[qt], zero4, 0, 0, 0);
                float4_t sB = __builtin_amdgcn_mfma_f32_16x16x32_bf16(KaB, Qf[qt], zero4, 0, 0, 0);
                float eA0 = __builtin_amdgcn_exp2f(sA.x), eA1 = __builtin_amdgcn_exp2f(sA.y);
                float eA2 = __builtin_amdgcn_exp2f(sA.z), eA3 = __builtin_amdgcn_exp2f(sA.w);
                float eB0 = __builtin_amdgcn_exp2f(sB.x), eB1 = __builtin_amdgcn_exp2f(sB.y);
                float eB2 = __builtin_amdgcn_exp2f(sB.z), eB3 = __builtin_amdgcn_exp2f(sB.w);
                lsum[qt] += ((eA0 + eA1) + (eA2 + eA3)) + ((eB0 + eB1) + (eB2 + eB3));
                // pack pairs (truncation) with one v_perm each: [lo16=e_even, hi16=e_odd]
                pa0[qt] = __builtin_amdgcn_perm(bitsu(eA1), bitsu(eA0), 0x07060302u);
                pa1[qt] = __builtin_amdgcn_perm(bitsu(eA3), bitsu(eA2), 0x07060302u);
                pb0[qt] = __builtin_amdgcn_perm(bitsu(eB1), bitsu(eB0), 0x07060302u);
                pb1[qt] = __builtin_amdgcn_perm(bitsu(eB3), bitsu(eB2), 0x07060302u);
            }
            // V^T A-fragments for this 32-key group
            int base = ch * 64 + g * 32 + q * 8;
            short8 Va0 = *reinterpret_cast<const short8*>(&Vt[mr * V520 + base]);
            short8 Va1 = *reinterpret_cast<const short8*>(&Vt[(16 + mr) * V520 + base]);
            #pragma unroll
            for (int qt = 0; qt < 2; ++qt) {
                // C-layout P (keys q*4+r) -> B-operand (keys q*8+j) in-register:
                // word w of dest lane (q,mr) comes from lane (q&1)*32+(w>>1)*16+mr
                // of pa (q<2) / pb (q>=2). Two swap stages produce two words each.
                uint2_t re = __builtin_amdgcn_permlane32_swap(pa0[qt], pb0[qt], 0, 0);
                uint2_t we = __builtin_amdgcn_permlane16_swap(re.x, re.y, 0, 0);   // {w0, w2}
                uint2_t ro = __builtin_amdgcn_permlane32_swap(pa1[qt], pb1[qt], 0, 0);
                uint2_t wo = __builtin_amdgcn_permlane16_swap(ro.x, ro.y, 0, 0);   // {w1, w3}
                int4_t pi = { (int)we.x, (int)wo.x, (int)we.y, (int)wo.y };
                short8 Pb = __builtin_bit_cast(short8, pi);
                acc[0][qt] = __builtin_amdgcn_mfma_f32_16x16x32_bf16(Va0, Pb, acc[0][qt], 0, 0, 0);
                acc[1][qt] = __builtin_amdgcn_mfma_f32_16x16x32_bf16(Va1, Pb, acc[1][qt], 0, 0, 0);
            }
        }
    }

    // softmax denominators: reduce across quads, invert
    float inv[2];
    #pragma unroll
    for (int qt = 0; qt < 2; ++qt) {
        float v = lsum[qt];
        v += __shfl_xor(v, 16);
        v += __shfl_xor(v, 32);
        inv[qt] = 1.0f / v;
    }

    // O store: lane holds O[qrow=row0+qt*16+mr][c = n*32 + dt*16 + q*4 + r]
    float* outb = out + (size_t)b * HW * 128 + nw * 8 * 128 + n * 32;
    #pragma unroll
    for (int qt = 0; qt < 2; ++qt) {
        int l = row0 + qt * 16 + mr;
        size_t basep = (size_t)((l >> 3) * 64 + (l & 7)) * 128;
        #pragma unroll
        for (int dt = 0; dt < 2; ++dt) {
            float4_t o = acc[dt][qt] * inv[qt];
            *reinterpret_cast<float4_t*>(outb + basep + dt * 16 + q * 4) = o;
        }
    }

    __syncthreads();   // O-stores visible block-wide; Kt/Vt stable (read-only)

    // ---- depthwise 3x3 conv + bias (window-local SAME pad) from LDS V, RMW out
    // 1024 threads = 64 h-rows x 16 channel-pairs; each thread 2 channels.
    int c2 = (t & 15) * 2;             // relative channel 0,2,..,30
    int h  = t >> 4;                   // 0..63
    float2_t outv[8];
    #pragma unroll
    for (int cc = 0; cc < 2; ++cc) {
        int c = c2 + cc;
        float w9[9];
        #pragma unroll
        for (int i = 0; i < 9; ++i) w9[i] = cw[(n * 32 + c) * 9 + i];
        float bias = cb[n * 32 + c];
        float rv[3][8];
        #pragma unroll
        for (int rr = 0; rr < 3; ++rr) {
            int hh = h - 1 + rr;
            if (hh >= 0 && hh < 64) {
                short8 u = *reinterpret_cast<const short8*>(&Vt[c * V520 + hh * 8]);
                #pragma unroll
                for (int j = 0; j < 8; ++j)
                    rv[rr][j] = bitsf(((unsigned)(unsigned short)u[j]) << 16);
            } else {
                #pragma unroll
                for (int j = 0; j < 8; ++j) rv[rr][j] = 0.f;
            }
        }
        #pragma unroll
        for (int w = 0; w < 8; ++w) {
            float o = bias;
            #pragma unroll
            for (int rr = 0; rr < 3; ++rr) {
                if (w > 0) o += rv[rr][w - 1] * w9[rr * 3 + 0];
                o += rv[rr][w] * w9[rr * 3 + 1];
                if (w < 7) o += rv[rr][w + 1] * w9[rr * 3 + 2];
            }
            outv[w][cc] = o;
        }
    }
    #pragma unroll
    for (int w = 0; w < 8; ++w) {
        size_t off = (size_t)h * 8192 + w * 128 + c2;
        float2_t cur = *reinterpret_cast<const float2_t*>(outb + off);
        cur += outv[w];
        *reinterpret_cast<float2_t*>(outb + off) = cur;
    }
}

extern "C" void kernel_launch(void* const* d_in, const int* in_sizes, int n_in,
                              void* d_out, int out_size, void* d_ws, size_t ws_size,
                              hipStream_t stream) {
    const float* temp = (const float*)d_in[0];
    const float* cw   = (const float*)d_in[1];
    const float* cb   = (const float*)d_in[2];
    float* out = (float*)d_out;
    hipLaunchKernelGGL(cswin_fused, dim3(512), dim3(1024), 0, stream, temp, cw, cb, out);
}